// Round 4
// baseline (2741.433 us; speedup 1.0000x reference)
//
#include <hip/hip_runtime.h>
#include <cstddef>
#include <cstdint>

typedef __attribute__((ext_vector_type(8))) short bf16x8;
typedef __attribute__((ext_vector_type(4))) float f32x4;
typedef unsigned int u32t;
typedef unsigned short u16t;

__device__ inline u16t f2bf(float f) {
  union { float f; unsigned u; } c; c.f = f;
  return (u16t)((c.u + 0x7FFFu + ((c.u >> 16) & 1u)) >> 16);
}
__device__ inline float ubits(u32t u) { union { u32t u; float f; } c; c.u = u; return c.f; }
__device__ inline float bf2f(u16t u) { return ubits(((u32t)u) << 16); }
__device__ inline float fsig(float x) { return __builtin_amdgcn_rcpf(1.f + __expf(-x)); }
__device__ inline float ftanh(float x) {
  float t = __expf(-2.f * fabsf(x));
  return copysignf((1.f - t) * __builtin_amdgcn_rcpf(1.f + t), x);
}

// bf16 weight mats, row-major [128][128]:
// 0: Wzf  1: Wzh  2: Wr  3: Whf  4: Whh  5: Ur
__global__ __launch_bounds__(256) void conv_weights(
    const float* __restrict__ Wz, const float* __restrict__ Wr,
    const float* __restrict__ Ur, const float* __restrict__ Wh,
    short* __restrict__ out)
{
  int i = blockIdx.x * 256 + threadIdx.x;
  if (i >= 6 * 16384) return;
  int mat = i >> 14, idx = i & 16383;
  int o = idx >> 7, c = idx & 127;
  float v = 0.f;
  switch (mat) {
    case 0: v = Wz[o * 256 + c];        break;
    case 1: v = Wz[o * 256 + 128 + c];  break;
    case 2: v = Wr[o * 128 + c];        break;
    case 3: v = Wh[o * 256 + c];        break;
    case 4: v = Wh[o * 256 + 128 + c];  break;
    case 5: v = Ur[o * 128 + c];        break;
  }
  out[i] = (short)f2bf(v);
}

__global__ __launch_bounds__(256) void conv_fmess(const float* __restrict__ src,
                                                  u16t* __restrict__ dst, size_t n8)
{
  size_t i = (size_t)blockIdx.x * 256 + threadIdx.x;
  if (i >= n8) return;
  const float4 a = *reinterpret_cast<const float4*>(src + i * 8);
  const float4 b = *reinterpret_cast<const float4*>(src + i * 8 + 4);
  uint4 o;
  o.x = ((u32t)f2bf(a.y) << 16) | f2bf(a.x);
  o.y = ((u32t)f2bf(a.w) << 16) | f2bf(a.z);
  o.z = ((u32t)f2bf(b.y) << 16) | f2bf(b.x);
  o.w = ((u32t)f2bf(b.w) << 16) | f2bf(b.z);
  *reinterpret_cast<uint4*>(dst + i * 8) = o;
}

// Detect whether bgraph arrived as int64 (odd 32-bit words all zero).
__global__ void detect64(const int* __restrict__ bg, int* __restrict__ flag) {
  int t = threadIdx.x;
  int v = bg[2 * t + 1];
  unsigned long long m = __ballot(v == 0);
  if (t == 0) *flag = (m == ~0ull) ? 1 : 0;
}

__global__ __launch_bounds__(256) void compact_bg(const int* __restrict__ bg,
                                                  const int* __restrict__ flag,
                                                  int* __restrict__ bg32, int n)
{
  int i = blockIdx.x * 256 + threadIdx.x;
  if (i < n) bg32[i] = (*flag) ? bg[2 * (size_t)i] : bg[i];
}

// LDS map (bytes):
//  [0,34816)      hbuf: 2 bufs x 4 waves x 4352 (16 rows x 272B padded)
//  [34816,43520)  s_fm  u16[32][136]
//  [43520,52224)  s_R1  u16[32][136]   (aliased by s_sb after chunk loop)
//  [52224,53248)  s_idx int[256]
// aliases (valid after the post-chunk barrier):
//  s_sum f32[32][132] @0 ; s_gb u16[32][136] @16896
//  outstage: MODE0/1 u16[32][128] @25600 ; MODE2 f32[32][128] @16896
template<int MODE>   // 0=first step (h=0), 1=middle (bf16 out), 2=last (fp32 out)
__global__ __launch_bounds__(256, 3) void step_k(
    const u16t* __restrict__ fmb,
    const int*  __restrict__ bg32,
    const u16t* __restrict__ hin,
    const short* __restrict__ wbf,
    const float* __restrict__ bz, const float* __restrict__ urb, const float* __restrict__ bh,
    u16t* __restrict__ houtb, float* __restrict__ houtf, int E)
{
  __shared__ __align__(16) char smem[53248];
  u16t*  s_fm  = (u16t*)(smem + 34816);
  u16t*  s_R1  = (u16t*)(smem + 43520);
  int*   s_idx = (int*)(smem + 52224);
  float* s_sum = (float*)(smem);
  u16t*  s_gb  = (u16t*)(smem + 16896);
  u16t*  s_sb  = (u16t*)(smem + 43520);

  const int tid = threadIdx.x, wave = tid >> 6, lane = tid & 63;
  const int cl = lane & 15, kg = lane >> 4;
  const int base = blockIdx.x * 32;
  const int mrow = (wave & 1) * 16, ncol = (wave >> 1) * 64;

  // ---- phase 1: fmess tile -> LDS ; neighbor indices -> LDS ----
  #pragma unroll
  for (int it = 0; it < 2; ++it) {
    int s = it * 256 + tid;
    int r = s >> 4, c = (s & 15) * 8;
    uint4 v = {0u, 0u, 0u, 0u};
    int e = base + r;
    if (e < E) v = *reinterpret_cast<const uint4*>(fmb + (size_t)e * 128 + c);
    *reinterpret_cast<uint4*>(s_fm + r * 136 + c) = v;
  }
  if (MODE != 0) {
    int gi = base * 8 + tid;
    s_idx[tid] = (gi < E * 8) ? bg32[gi] : 0;
  }
  __syncthreads();

  const short* Wzf = wbf;
  const short* Wzh = wbf + 16384;
  const short* Wr  = wbf + 2 * 16384;
  const short* Whf = wbf + 3 * 16384;
  const short* Whh = wbf + 4 * 16384;
  const short* Ur  = wbf + 5 * 16384;

  // ---- phase 2: R1 = fmess @ Wr^T + urb -> LDS bf16 ----
  if (MODE != 0) {
    bf16x8 af[4];
    #pragma unroll
    for (int ks = 0; ks < 4; ++ks)
      af[ks] = *reinterpret_cast<const bf16x8*>(s_fm + (mrow + cl) * 136 + ks * 32 + kg * 8);
    f32x4 racc[4];
    #pragma unroll
    for (int nt = 0; nt < 4; ++nt) racc[nt] = (f32x4){0, 0, 0, 0};
    #pragma unroll
    for (int ks = 0; ks < 4; ++ks) {
      #pragma unroll
      for (int nt = 0; nt < 4; ++nt) {
        bf16x8 b = *reinterpret_cast<const bf16x8*>(Wr + (size_t)(ncol + nt * 16 + cl) * 128 + ks * 32 + kg * 8);
        racc[nt] = __builtin_amdgcn_mfma_f32_16x16x32_bf16(af[ks], b, racc[nt], 0, 0, 0);
      }
    }
    #pragma unroll
    for (int nt = 0; nt < 4; ++nt) {
      int n = ncol + nt * 16 + cl;
      float bias = urb[n];
      #pragma unroll
      for (int r = 0; r < 4; ++r)
        s_R1[(mrow + kg * 4 + r) * 136 + n] = f2bf(racc[nt][r] + bias);
    }
    __syncthreads();
  }

  // ---- phase 3: chunked gather (h only) + on-the-fly P + sigma-gated sums ----
  float sumh[2][8], sumg[2][8];
  #pragma unroll
  for (int a = 0; a < 2; ++a)
    #pragma unroll
    for (int nt = 0; nt < 8; ++nt) { sumh[a][nt] = 0.f; sumg[a][nt] = 0.f; }

  if (MODE != 0) {
    char* hb0 = smem + wave * 4352;
    char* hb1 = smem + 17408 + wave * 4352;
    uint4 stg[4];

    auto ISSUE = [&](int c) {
      #pragma unroll
      for (int c4 = 0; c4 < 4; ++c4) {
        int rl = c4 * 4 + kg;
        int ent = (wave * 8 + (rl >> 1)) * 8 + 2 * c + (rl & 1);
        int idx = s_idx[ent];
        stg[c4] = *reinterpret_cast<const uint4*>(hin + (size_t)idx * 128 + cl * 8);
      }
    };
    auto WRITE = [&](char* b) {
      #pragma unroll
      for (int c4 = 0; c4 < 4; ++c4)
        *reinterpret_cast<uint4*>(b + (c4 * 4 + kg) * 272 + cl * 16) = stg[c4];
    };

    ISSUE(0);
    WRITE(hb0);
    #pragma unroll
    for (int c = 0; c < 4; ++c) {
      char* cb = (c & 1) ? hb1 : hb0;
      if (c < 3) ISSUE(c + 1);                       // next chunk's loads in flight
      bf16x8 an[4];
      #pragma unroll
      for (int ks = 0; ks < 4; ++ks)
        an[ks] = *reinterpret_cast<const bf16x8*>(cb + cl * 272 + ks * 64 + kg * 16);
      f32x4 pac[8];
      #pragma unroll
      for (int nt = 0; nt < 8; ++nt) pac[nt] = (f32x4){0, 0, 0, 0};
      #pragma unroll
      for (int ks = 0; ks < 4; ++ks) {
        #pragma unroll
        for (int nt = 0; nt < 8; ++nt) {
          bf16x8 b = *reinterpret_cast<const bf16x8*>(Ur + (size_t)(nt * 16 + cl) * 128 + ks * 32 + kg * 8);
          pac[nt] = __builtin_amdgcn_mfma_f32_16x16x32_bf16(an[ks], b, pac[nt], 0, 0, 0);
        }
      }
      #pragma unroll
      for (int nt = 0; nt < 8; ++nt) {
        int n = nt * 16 + cl;
        #pragma unroll
        for (int r = 0; r < 4; ++r) {
          int rl = kg * 4 + r;
          int e = wave * 8 + (rl >> 1);
          float r1 = bf2f(s_R1[e * 136 + n]);
          float hv = bf2f(*reinterpret_cast<const u16t*>(cb + rl * 272 + 2 * n));
          float sg = fsig(r1 + pac[nt][r]);
          sumh[r >> 1][nt] += hv;
          sumg[r >> 1][nt] += sg * hv;
        }
      }
      if (c < 3) WRITE((c & 1) ? hb0 : hb1);
    }
    __syncthreads();   // all hbuf / s_R1 reads complete (everywhere)

    #pragma unroll
    for (int a = 0; a < 2; ++a) {
      int e = wave * 8 + kg * 2 + a;
      #pragma unroll
      for (int nt = 0; nt < 8; ++nt) {
        int n = nt * 16 + cl;
        s_sum[e * 132 + n] = sumh[a][nt];
        s_sb[e * 136 + n] = f2bf(sumh[a][nt]);
        s_gb[e * 136 + n] = f2bf(sumg[a][nt]);
      }
    }
    __syncthreads();
  }

  // ---- phase 4: fmess projections Zf/Hf + hidden-state GEMMs ----
  bf16x8 af[4];
  #pragma unroll
  for (int ks = 0; ks < 4; ++ks)
    af[ks] = *reinterpret_cast<const bf16x8*>(s_fm + (mrow + cl) * 136 + ks * 32 + kg * 8);

  f32x4 zacc[4], hacc[4], accz[4], acch[4];
  #pragma unroll
  for (int nt = 0; nt < 4; ++nt) {
    zacc[nt] = (f32x4){0, 0, 0, 0}; hacc[nt] = (f32x4){0, 0, 0, 0};
    accz[nt] = (f32x4){0, 0, 0, 0}; acch[nt] = (f32x4){0, 0, 0, 0};
  }
  #pragma unroll
  for (int ks = 0; ks < 4; ++ks) {
    #pragma unroll
    for (int nt = 0; nt < 4; ++nt) {
      int n = ncol + nt * 16 + cl;
      bf16x8 b1 = *reinterpret_cast<const bf16x8*>(Wzf + (size_t)n * 128 + ks * 32 + kg * 8);
      zacc[nt] = __builtin_amdgcn_mfma_f32_16x16x32_bf16(af[ks], b1, zacc[nt], 0, 0, 0);
      bf16x8 b2 = *reinterpret_cast<const bf16x8*>(Whf + (size_t)n * 128 + ks * 32 + kg * 8);
      hacc[nt] = __builtin_amdgcn_mfma_f32_16x16x32_bf16(af[ks], b2, hacc[nt], 0, 0, 0);
    }
  }
  if (MODE != 0) {
    bf16x8 az[4], ag[4];
    #pragma unroll
    for (int ks = 0; ks < 4; ++ks) {
      az[ks] = *reinterpret_cast<const bf16x8*>(s_sb + (mrow + cl) * 136 + ks * 32 + kg * 8);
      ag[ks] = *reinterpret_cast<const bf16x8*>(s_gb + (mrow + cl) * 136 + ks * 32 + kg * 8);
    }
    #pragma unroll
    for (int ks = 0; ks < 4; ++ks) {
      #pragma unroll
      for (int nt = 0; nt < 4; ++nt) {
        int n = ncol + nt * 16 + cl;
        bf16x8 b1 = *reinterpret_cast<const bf16x8*>(Wzh + (size_t)n * 128 + ks * 32 + kg * 8);
        accz[nt] = __builtin_amdgcn_mfma_f32_16x16x32_bf16(az[ks], b1, accz[nt], 0, 0, 0);
        bf16x8 b2 = *reinterpret_cast<const bf16x8*>(Whh + (size_t)n * 128 + ks * 32 + kg * 8);
        acch[nt] = __builtin_amdgcn_mfma_f32_16x16x32_bf16(ag[ks], b2, acch[nt], 0, 0, 0);
      }
    }
  }

  // ---- phase 5: GRU epilogue ----
  float nh_sv[4][4];
  #pragma unroll
  for (int nt = 0; nt < 4; ++nt) {
    int n = ncol + nt * 16 + cl;
    float bzv = bz[n], bhv = bh[n];
    #pragma unroll
    for (int r = 0; r < 4; ++r) {
      int rowt = mrow + kg * 4 + r;
      int e = base + rowt;
      float z   = fsig(zacc[nt][r] + accz[nt][r] + bzv);
      float pre = ftanh(hacc[nt][r] + acch[nt][r] + bhv);
      float sh  = (MODE == 0) ? 0.f : s_sum[rowt * 132 + n];
      float nh  = (1.f - z) * sh + z * pre;
      if (e == 0) nh = 0.f;
      nh_sv[nt][r] = nh;
    }
  }

  // ---- phase 6: stage + coalesced store ----
  if (MODE == 2) {
    __syncthreads();   // s_gb frag reads + s_sum reads complete before overwrite
    float* so = (float*)(smem + 16896);
    #pragma unroll
    for (int nt = 0; nt < 4; ++nt) {
      int n = ncol + nt * 16 + cl;
      #pragma unroll
      for (int r = 0; r < 4; ++r)
        so[(mrow + kg * 4 + r) * 128 + n] = nh_sv[nt][r];
    }
    __syncthreads();
    #pragma unroll
    for (int it = 0; it < 4; ++it) {
      int slot = it * 256 + tid;
      int row = slot >> 5, seg = slot & 31;
      if (base + row < E)
        *reinterpret_cast<float4*>(houtf + (size_t)(base + row) * 128 + seg * 4) =
            *reinterpret_cast<const float4*>(so + row * 128 + seg * 4);
    }
  } else {
    u16t* so = (u16t*)(smem + 25600);
    #pragma unroll
    for (int nt = 0; nt < 4; ++nt) {
      int n = ncol + nt * 16 + cl;
      #pragma unroll
      for (int r = 0; r < 4; ++r)
        so[(mrow + kg * 4 + r) * 128 + n] = f2bf(nh_sv[nt][r]);
    }
    __syncthreads();
    #pragma unroll
    for (int it = 0; it < 2; ++it) {
      int slot = it * 256 + tid;
      int row = slot >> 4, seg = slot & 15;
      if (base + row < E)
        *reinterpret_cast<uint4*>(houtb + (size_t)(base + row) * 128 + seg * 8) =
            *reinterpret_cast<const uint4*>(so + row * 128 + seg * 8);
    }
  }
}

extern "C" void kernel_launch(void* const* d_in, const int* in_sizes, int n_in,
                              void* d_out, int out_size, void* d_ws, size_t ws_size,
                              hipStream_t stream) {
  const float* fmess = (const float*)d_in[0];
  const int*   bg    = (const int*)d_in[1];
  const float* Wz    = (const float*)d_in[2];
  const float* bz    = (const float*)d_in[3];
  const float* Wrw   = (const float*)d_in[4];
  const float* Urw   = (const float*)d_in[5];
  const float* urb   = (const float*)d_in[6];
  const float* Wh    = (const float*)d_in[7];
  const float* bh    = (const float*)d_in[8];
  float* out = (float*)d_out;

  const int E = in_sizes[0] / 128;
  const size_t EH = (size_t)E * 128;

  // ws: hA (EH u16) | fmb (EH u16) | bg32 (E*8 int) | wbf (6*16384 short) | flag
  u16t* hA   = (u16t*)d_ws;
  u16t* fmb  = hA + EH;
  int*  bg32 = (int*)(fmb + EH);
  short* wbf = (short*)(bg32 + (size_t)E * 8);
  int*  flag = (int*)(wbf + 6 * 16384);
  // hB lives in the first half of d_out (dead by the time step 4 overwrites it)
  u16t* hB = (u16t*)d_out;

  conv_weights<<<384, 256, 0, stream>>>(Wz, Wrw, Urw, Wh, wbf);
  detect64<<<1, 64, 0, stream>>>(bg, flag);
  compact_bg<<<(E * 8 + 255) / 256, 256, 0, stream>>>(bg, flag, bg32, E * 8);
  conv_fmess<<<(int)((EH / 8 + 255) / 256), 256, 0, stream>>>(fmess, fmb, EH / 8);

  const int grid = (E + 31) / 32;
  // s0 -> hB ; s1 hB->hA ; s2 hA->hB ; s3 hB->hA ; s4 hA -> fp32 out
  step_k<0><<<grid, 256, 0, stream>>>(fmb, bg32, hA, wbf, bz, urb, bh, hB, nullptr, E);
  step_k<1><<<grid, 256, 0, stream>>>(fmb, bg32, hB, wbf, bz, urb, bh, hA, nullptr, E);
  step_k<1><<<grid, 256, 0, stream>>>(fmb, bg32, hA, wbf, bz, urb, bh, hB, nullptr, E);
  step_k<1><<<grid, 256, 0, stream>>>(fmb, bg32, hB, wbf, bz, urb, bh, hA, nullptr, E);
  step_k<2><<<grid, 256, 0, stream>>>(fmb, bg32, hA, wbf, bz, urb, bh, nullptr, out, E);
}

// Round 5
// 2487.812 us; speedup vs baseline: 1.1019x; 1.1019x over previous
//
#include <hip/hip_runtime.h>
#include <cstddef>
#include <cstdint>

typedef __attribute__((ext_vector_type(8))) short bf16x8;
typedef __attribute__((ext_vector_type(4))) float f32x4;
typedef unsigned int u32t;
typedef unsigned short u16t;

__device__ inline u16t f2bf(float f) {
  union { float f; unsigned u; } c; c.f = f;
  return (u16t)((c.u + 0x7FFFu + ((c.u >> 16) & 1u)) >> 16);
}
__device__ inline float ubits(u32t u) { union { u32t u; float f; } c; c.u = u; return c.f; }
__device__ inline float bf2f(u16t u) { return ubits(((u32t)u) << 16); }
__device__ inline float fsig(float x) { return __builtin_amdgcn_rcpf(1.f + __expf(-x)); }
__device__ inline float ftanh(float x) {
  float t = __expf(-2.f * fabsf(x));
  return copysignf((1.f - t) * __builtin_amdgcn_rcpf(1.f + t), x);
}

// bf16 weight mats, row-major [128][128]:
// 0: Wzf  1: Wzh  2: Wr  3: Whf  4: Whh  5: Ur
__global__ __launch_bounds__(256) void conv_weights(
    const float* __restrict__ Wz, const float* __restrict__ Wr,
    const float* __restrict__ Ur, const float* __restrict__ Wh,
    short* __restrict__ out)
{
  int i = blockIdx.x * 256 + threadIdx.x;
  if (i >= 6 * 16384) return;
  int mat = i >> 14, idx = i & 16383;
  int o = idx >> 7, c = idx & 127;
  float v = 0.f;
  switch (mat) {
    case 0: v = Wz[o * 256 + c];        break;
    case 1: v = Wz[o * 256 + 128 + c];  break;
    case 2: v = Wr[o * 128 + c];        break;
    case 3: v = Wh[o * 256 + c];        break;
    case 4: v = Wh[o * 256 + 128 + c];  break;
    case 5: v = Ur[o * 128 + c];        break;
  }
  out[i] = (short)f2bf(v);
}

__global__ __launch_bounds__(256) void conv_fmess(const float* __restrict__ src,
                                                  u16t* __restrict__ dst, size_t n8)
{
  size_t i = (size_t)blockIdx.x * 256 + threadIdx.x;
  if (i >= n8) return;
  const float4 a = *reinterpret_cast<const float4*>(src + i * 8);
  const float4 b = *reinterpret_cast<const float4*>(src + i * 8 + 4);
  uint4 o;
  o.x = ((u32t)f2bf(a.y) << 16) | f2bf(a.x);
  o.y = ((u32t)f2bf(a.w) << 16) | f2bf(a.z);
  o.z = ((u32t)f2bf(b.y) << 16) | f2bf(b.x);
  o.w = ((u32t)f2bf(b.w) << 16) | f2bf(b.z);
  *reinterpret_cast<uint4*>(dst + i * 8) = o;
}

// Detect whether bgraph arrived as int64 (odd 32-bit words all zero).
__global__ void detect64(const int* __restrict__ bg, int* __restrict__ flag) {
  int t = threadIdx.x;
  int v = bg[2 * t + 1];
  unsigned long long m = __ballot(v == 0);
  if (t == 0) *flag = (m == ~0ull) ? 1 : 0;
}

__global__ __launch_bounds__(256) void compact_bg(const int* __restrict__ bg,
                                                  const int* __restrict__ flag,
                                                  int* __restrict__ bg32, int n)
{
  int i = blockIdx.x * 256 + threadIdx.x;
  if (i < n) bg32[i] = (*flag) ? bg[2 * (size_t)i] : bg[i];
}

// Issue tile T's gather: lane (cl,kg) loads 4x16B A-fragments of neighbor row idx[T*16+cl].
#define ISSUE_T(B, T) { \
  int idx_ = s_idx[wave * 64 + (T) * 16 + cl]; \
  const u16t* rp_ = hin + (size_t)idx_ * 128 + kg * 8; \
  B##0 = *reinterpret_cast<const uint4*>(rp_); \
  B##1 = *reinterpret_cast<const uint4*>(rp_ + 32); \
  B##2 = *reinterpret_cast<const uint4*>(rp_ + 64); \
  B##3 = *reinterpret_cast<const uint4*>(rp_ + 96); \
}

// Process tile T from staged regs: LDS drop, P = htile @ Ur^T via MFMA, sigma-gated sums.
#define PROC_T(B, T) { \
  *reinterpret_cast<uint4*>(hb + cl * 272 + kg * 16)       = B##0; \
  *reinterpret_cast<uint4*>(hb + cl * 272 + kg * 16 + 64)  = B##1; \
  *reinterpret_cast<uint4*>(hb + cl * 272 + kg * 16 + 128) = B##2; \
  *reinterpret_cast<uint4*>(hb + cl * 272 + kg * 16 + 192) = B##3; \
  f32x4 pac[8]; \
  _Pragma("unroll") for (int nt = 0; nt < 8; ++nt) pac[nt] = (f32x4){0.f, 0.f, 0.f, 0.f}; \
  { bf16x8 an = *reinterpret_cast<const bf16x8*>(&B##0); \
    _Pragma("unroll") for (int nt = 0; nt < 8; ++nt) { \
      bf16x8 bb = *reinterpret_cast<const bf16x8*>(Ur + (size_t)(nt * 16 + cl) * 128 + kg * 8); \
      pac[nt] = __builtin_amdgcn_mfma_f32_16x16x32_bf16(an, bb, pac[nt], 0, 0, 0); } } \
  { bf16x8 an = *reinterpret_cast<const bf16x8*>(&B##1); \
    _Pragma("unroll") for (int nt = 0; nt < 8; ++nt) { \
      bf16x8 bb = *reinterpret_cast<const bf16x8*>(Ur + (size_t)(nt * 16 + cl) * 128 + 32 + kg * 8); \
      pac[nt] = __builtin_amdgcn_mfma_f32_16x16x32_bf16(an, bb, pac[nt], 0, 0, 0); } } \
  { bf16x8 an = *reinterpret_cast<const bf16x8*>(&B##2); \
    _Pragma("unroll") for (int nt = 0; nt < 8; ++nt) { \
      bf16x8 bb = *reinterpret_cast<const bf16x8*>(Ur + (size_t)(nt * 16 + cl) * 128 + 64 + kg * 8); \
      pac[nt] = __builtin_amdgcn_mfma_f32_16x16x32_bf16(an, bb, pac[nt], 0, 0, 0); } } \
  { bf16x8 an = *reinterpret_cast<const bf16x8*>(&B##3); \
    _Pragma("unroll") for (int nt = 0; nt < 8; ++nt) { \
      bf16x8 bb = *reinterpret_cast<const bf16x8*>(Ur + (size_t)(nt * 16 + cl) * 128 + 96 + kg * 8); \
      pac[nt] = __builtin_amdgcn_mfma_f32_16x16x32_bf16(an, bb, pac[nt], 0, 0, 0); } } \
  { int er_ = wave * 8 + 2 * (T) + (kg >> 1); \
    _Pragma("unroll") for (int nt = 0; nt < 8; ++nt) { \
      int n_ = nt * 16 + cl; \
      float r1_ = bf2f(s_R1[er_ * 136 + n_]); \
      _Pragma("unroll") for (int rg = 0; rg < 4; ++rg) { \
        float hv_ = bf2f(*reinterpret_cast<const u16t*>(hb + (kg * 4 + rg) * 272 + 2 * n_)); \
        float sg_ = fsig(r1_ + pac[nt][rg]); \
        shacc[T][nt] += hv_; \
        sgacc[T][nt] += sg_ * hv_; \
      } } } \
}

// LDS map (bytes):
//  [0,17408)       htile: 4 waves x (16 rows x 272B)   [aliased by out-stage at end]
//  [17408,26112)   s_fm  u16[32][136]
//  [26112,34816)   s_R1  u16[32][136]
//  [34816,35840)   s_idx int[256]
//  [35840,44544)   s_sb  u16[32][136]
//  [44544,53248)   s_gb  u16[32][136]
template<int MODE>   // 0=first step (h=0), 1=middle (bf16 out), 2=last (fp32 out)
__global__ __launch_bounds__(256) void step_k(
    const u16t* __restrict__ fmb,
    const int*  __restrict__ bg32,
    const u16t* __restrict__ hin,
    const short* __restrict__ wbf,
    const float* __restrict__ bz, const float* __restrict__ urb, const float* __restrict__ bh,
    u16t* __restrict__ houtb, float* __restrict__ houtf, int E)
{
  __shared__ __align__(16) char smem[53248];
  u16t* s_fm  = (u16t*)(smem + 17408);
  u16t* s_R1  = (u16t*)(smem + 26112);
  int*  s_idx = (int*)(smem + 34816);
  u16t* s_sb  = (u16t*)(smem + 35840);
  u16t* s_gb  = (u16t*)(smem + 44544);

  const int tid = threadIdx.x, wave = tid >> 6, lane = tid & 63;
  const int cl = lane & 15, kg = lane >> 4;
  const int base = blockIdx.x * 32;
  const int mrow = (wave & 1) * 16, ncol = (wave >> 1) * 64;
  char* hb = smem + wave * 4352;

  // ---- phase 1: fmess tile -> LDS ; neighbor indices -> LDS ----
  #pragma unroll
  for (int it = 0; it < 2; ++it) {
    int s = it * 256 + tid;
    int r = s >> 4, c = (s & 15) * 8;
    uint4 v = {0u, 0u, 0u, 0u};
    int e = base + r;
    if (e < E) v = *reinterpret_cast<const uint4*>(fmb + (size_t)e * 128 + c);
    *reinterpret_cast<uint4*>(s_fm + r * 136 + c) = v;
  }
  if (MODE != 0) {
    int gi = base * 8 + tid;
    s_idx[tid] = (gi < E * 8) ? bg32[gi] : 0;
  }
  __syncthreads();

  const short* Wzf = wbf;
  const short* Wzh = wbf + 16384;
  const short* Wr  = wbf + 2 * 16384;
  const short* Whf = wbf + 3 * 16384;
  const short* Whh = wbf + 4 * 16384;
  const short* Ur  = wbf + 5 * 16384;

  bf16x8 af[4];
  #pragma unroll
  for (int ks = 0; ks < 4; ++ks)
    af[ks] = *reinterpret_cast<const bf16x8*>(s_fm + (mrow + cl) * 136 + ks * 32 + kg * 8);

  float shacc[4][8], sgacc[4][8];
  #pragma unroll
  for (int T = 0; T < 4; ++T)
    #pragma unroll
    for (int nt = 0; nt < 8; ++nt) { shacc[T][nt] = 0.f; sgacc[T][nt] = 0.f; }

  if (MODE != 0) {
    // kick tile-0 loads, hide them under the R1 GEMM
    uint4 bufA0, bufA1, bufA2, bufA3, bufB0, bufB1, bufB2, bufB3;
    ISSUE_T(bufA, 0);

    // ---- phase 2: R1 = fmess @ Wr^T + urb -> LDS bf16 ----
    {
      f32x4 racc[4];
      #pragma unroll
      for (int nt = 0; nt < 4; ++nt) racc[nt] = (f32x4){0.f, 0.f, 0.f, 0.f};
      #pragma unroll
      for (int ks = 0; ks < 4; ++ks) {
        #pragma unroll
        for (int nt = 0; nt < 4; ++nt) {
          bf16x8 b = *reinterpret_cast<const bf16x8*>(Wr + (size_t)(ncol + nt * 16 + cl) * 128 + ks * 32 + kg * 8);
          racc[nt] = __builtin_amdgcn_mfma_f32_16x16x32_bf16(af[ks], b, racc[nt], 0, 0, 0);
        }
      }
      #pragma unroll
      for (int nt = 0; nt < 4; ++nt) {
        int n = ncol + nt * 16 + cl;
        float bias = urb[n];
        #pragma unroll
        for (int r = 0; r < 4; ++r)
          s_R1[(mrow + kg * 4 + r) * 136 + n] = f2bf(racc[nt][r] + bias);
      }
    }
    __syncthreads();

    // ---- phase 3: 4 neighbor tiles, register double-buffered ----
    ISSUE_T(bufB, 1);
    PROC_T(bufA, 0);
    ISSUE_T(bufA, 2);
    PROC_T(bufB, 1);
    ISSUE_T(bufB, 3);
    PROC_T(bufA, 2);
    PROC_T(bufB, 3);

    // combine halves (lanes l and l^16 hold complementary 4-neighbor partials)
    #pragma unroll
    for (int T = 0; T < 4; ++T) {
      int er = wave * 8 + 2 * T + (kg >> 1);
      #pragma unroll
      for (int nt = 0; nt < 8; ++nt) {
        float sh = shacc[T][nt] + __shfl_xor(shacc[T][nt], 16);
        float sg = sgacc[T][nt] + __shfl_xor(sgacc[T][nt], 16);
        if ((kg & 1) == 0) {
          int n = nt * 16 + cl;
          s_sb[er * 136 + n] = f2bf(sh);
          s_gb[er * 136 + n] = f2bf(sg);
        }
      }
    }
    __syncthreads();
  }

  // ---- phase 4: Zf/Hf fmess projections + z/h hidden-state GEMMs ----
  f32x4 zacc[4], hacc[4], accz[4], acch[4];
  #pragma unroll
  for (int nt = 0; nt < 4; ++nt) {
    zacc[nt] = (f32x4){0.f, 0.f, 0.f, 0.f}; hacc[nt] = (f32x4){0.f, 0.f, 0.f, 0.f};
    accz[nt] = (f32x4){0.f, 0.f, 0.f, 0.f}; acch[nt] = (f32x4){0.f, 0.f, 0.f, 0.f};
  }
  #pragma unroll
  for (int ks = 0; ks < 4; ++ks) {
    #pragma unroll
    for (int nt = 0; nt < 4; ++nt) {
      int n = ncol + nt * 16 + cl;
      bf16x8 b1 = *reinterpret_cast<const bf16x8*>(Wzf + (size_t)n * 128 + ks * 32 + kg * 8);
      zacc[nt] = __builtin_amdgcn_mfma_f32_16x16x32_bf16(af[ks], b1, zacc[nt], 0, 0, 0);
      bf16x8 b2 = *reinterpret_cast<const bf16x8*>(Whf + (size_t)n * 128 + ks * 32 + kg * 8);
      hacc[nt] = __builtin_amdgcn_mfma_f32_16x16x32_bf16(af[ks], b2, hacc[nt], 0, 0, 0);
    }
  }
  if (MODE != 0) {
    bf16x8 az[4], ag[4];
    #pragma unroll
    for (int ks = 0; ks < 4; ++ks) {
      az[ks] = *reinterpret_cast<const bf16x8*>(s_sb + (mrow + cl) * 136 + ks * 32 + kg * 8);
      ag[ks] = *reinterpret_cast<const bf16x8*>(s_gb + (mrow + cl) * 136 + ks * 32 + kg * 8);
    }
    #pragma unroll
    for (int ks = 0; ks < 4; ++ks) {
      #pragma unroll
      for (int nt = 0; nt < 4; ++nt) {
        int n = ncol + nt * 16 + cl;
        bf16x8 b1 = *reinterpret_cast<const bf16x8*>(Wzh + (size_t)n * 128 + ks * 32 + kg * 8);
        accz[nt] = __builtin_amdgcn_mfma_f32_16x16x32_bf16(az[ks], b1, accz[nt], 0, 0, 0);
        bf16x8 b2 = *reinterpret_cast<const bf16x8*>(Whh + (size_t)n * 128 + ks * 32 + kg * 8);
        acch[nt] = __builtin_amdgcn_mfma_f32_16x16x32_bf16(ag[ks], b2, acch[nt], 0, 0, 0);
      }
    }
  }

  // ---- phase 5: GRU epilogue ----
  float nh_sv[4][4];
  #pragma unroll
  for (int nt = 0; nt < 4; ++nt) {
    int n = ncol + nt * 16 + cl;
    float bzv = bz[n], bhv = bh[n];
    #pragma unroll
    for (int r = 0; r < 4; ++r) {
      int rowt = mrow + kg * 4 + r;
      int e = base + rowt;
      float z   = fsig(zacc[nt][r] + accz[nt][r] + bzv);
      float pre = ftanh(hacc[nt][r] + acch[nt][r] + bhv);
      float sh  = (MODE == 0) ? 0.f : bf2f(s_sb[rowt * 136 + n]);
      float nh  = (1.f - z) * sh + z * pre;
      if (e == 0) nh = 0.f;
      nh_sv[nt][r] = nh;
    }
  }

  // ---- phase 6: stage (aliases htile region, dead since phase-3 barrier) + store ----
  if (MODE == 2) {
    float* so = (float*)(smem);
    #pragma unroll
    for (int nt = 0; nt < 4; ++nt) {
      int n = ncol + nt * 16 + cl;
      #pragma unroll
      for (int r = 0; r < 4; ++r)
        so[(mrow + kg * 4 + r) * 128 + n] = nh_sv[nt][r];
    }
    __syncthreads();
    #pragma unroll
    for (int it = 0; it < 4; ++it) {
      int slot = it * 256 + tid;
      int row = slot >> 5, seg = slot & 31;
      if (base + row < E)
        *reinterpret_cast<float4*>(houtf + (size_t)(base + row) * 128 + seg * 4) =
            *reinterpret_cast<const float4*>(so + row * 128 + seg * 4);
    }
  } else {
    u16t* so = (u16t*)(smem);
    #pragma unroll
    for (int nt = 0; nt < 4; ++nt) {
      int n = ncol + nt * 16 + cl;
      #pragma unroll
      for (int r = 0; r < 4; ++r)
        so[(mrow + kg * 4 + r) * 128 + n] = f2bf(nh_sv[nt][r]);
    }
    __syncthreads();
    #pragma unroll
    for (int it = 0; it < 2; ++it) {
      int slot = it * 256 + tid;
      int row = slot >> 4, seg = slot & 15;
      if (base + row < E)
        *reinterpret_cast<uint4*>(houtb + (size_t)(base + row) * 128 + seg * 8) =
            *reinterpret_cast<const uint4*>(so + row * 128 + seg * 8);
    }
  }
}

extern "C" void kernel_launch(void* const* d_in, const int* in_sizes, int n_in,
                              void* d_out, int out_size, void* d_ws, size_t ws_size,
                              hipStream_t stream) {
  const float* fmess = (const float*)d_in[0];
  const int*   bg    = (const int*)d_in[1];
  const float* Wz    = (const float*)d_in[2];
  const float* bz    = (const float*)d_in[3];
  const float* Wrw   = (const float*)d_in[4];
  const float* Urw   = (const float*)d_in[5];
  const float* urb   = (const float*)d_in[6];
  const float* Wh    = (const float*)d_in[7];
  const float* bh    = (const float*)d_in[8];
  float* out = (float*)d_out;

  const int E = in_sizes[0] / 128;
  const size_t EH = (size_t)E * 128;

  // ws: hA (EH u16) | fmb (EH u16) | bg32 (E*8 int) | wbf (6*16384 short) | flag
  u16t* hA   = (u16t*)d_ws;
  u16t* fmb  = hA + EH;
  int*  bg32 = (int*)(fmb + EH);
  short* wbf = (short*)(bg32 + (size_t)E * 8);
  int*  flag = (int*)(wbf + 6 * 16384);
  // hB lives in the first half of d_out (dead by the time the last step overwrites it)
  u16t* hB = (u16t*)d_out;

  conv_weights<<<384, 256, 0, stream>>>(Wz, Wrw, Urw, Wh, wbf);
  detect64<<<1, 64, 0, stream>>>(bg, flag);
  compact_bg<<<(E * 8 + 255) / 256, 256, 0, stream>>>(bg, flag, bg32, E * 8);
  conv_fmess<<<(int)((EH / 8 + 255) / 256), 256, 0, stream>>>(fmess, fmb, EH / 8);

  const int grid = (E + 31) / 32;
  // s0 -> hB ; s1 hB->hA ; s2 hA->hB ; s3 hB->hA ; s4 hA -> fp32 out
  step_k<0><<<grid, 256, 0, stream>>>(fmb, bg32, hA, wbf, bz, urb, bh, hB, nullptr, E);
  step_k<1><<<grid, 256, 0, stream>>>(fmb, bg32, hB, wbf, bz, urb, bh, hA, nullptr, E);
  step_k<1><<<grid, 256, 0, stream>>>(fmb, bg32, hA, wbf, bz, urb, bh, hB, nullptr, E);
  step_k<1><<<grid, 256, 0, stream>>>(fmb, bg32, hB, wbf, bz, urb, bh, hA, nullptr, E);
  step_k<2><<<grid, 256, 0, stream>>>(fmb, bg32, hA, wbf, bz, urb, bh, nullptr, out, E);
}

// Round 6
// 1127.370 us; speedup vs baseline: 2.4317x; 2.2067x over previous
//
#include <hip/hip_runtime.h>
#include <cstddef>
#include <cstdint>

typedef __attribute__((ext_vector_type(8))) short bf16x8;
typedef __attribute__((ext_vector_type(4))) float f32x4;
typedef unsigned int u32t;
typedef unsigned short u16t;

__device__ inline u16t f2bf(float f) {
  union { float f; unsigned u; } c; c.f = f;
  return (u16t)((c.u + 0x7FFFu + ((c.u >> 16) & 1u)) >> 16);
}
__device__ inline float ubits(u32t u) { union { u32t u; float f; } c; c.u = u; return c.f; }
__device__ inline float bf2f(u16t u) { return ubits(((u32t)u) << 16); }
__device__ inline float fsig(float x) { return __builtin_amdgcn_rcpf(1.f + __expf(-x)); }
__device__ inline float ftanh(float x) {
  float t = __expf(-2.f * fabsf(x));
  return copysignf((1.f - t) * __builtin_amdgcn_rcpf(1.f + t), x);
}

// bf16 weight mats, row-major [128][128]:
// 0: Wzf  1: Wzh  2: Wr  3: Whf  4: Whh  5: Ur
__global__ __launch_bounds__(256) void conv_weights(
    const float* __restrict__ Wz, const float* __restrict__ Wr,
    const float* __restrict__ Ur, const float* __restrict__ Wh,
    short* __restrict__ out)
{
  int i = blockIdx.x * 256 + threadIdx.x;
  if (i >= 6 * 16384) return;
  int mat = i >> 14, idx = i & 16383;
  int o = idx >> 7, c = idx & 127;
  float v = 0.f;
  switch (mat) {
    case 0: v = Wz[o * 256 + c];        break;
    case 1: v = Wz[o * 256 + 128 + c];  break;
    case 2: v = Wr[o * 128 + c];        break;
    case 3: v = Wh[o * 256 + c];        break;
    case 4: v = Wh[o * 256 + 128 + c];  break;
    case 5: v = Ur[o * 128 + c];        break;
  }
  out[i] = (short)f2bf(v);
}

__global__ __launch_bounds__(256) void conv_fmess(const float* __restrict__ src,
                                                  u16t* __restrict__ dst, size_t n8)
{
  size_t i = (size_t)blockIdx.x * 256 + threadIdx.x;
  if (i >= n8) return;
  const float4 a = *reinterpret_cast<const float4*>(src + i * 8);
  const float4 b = *reinterpret_cast<const float4*>(src + i * 8 + 4);
  uint4 o;
  o.x = ((u32t)f2bf(a.y) << 16) | f2bf(a.x);
  o.y = ((u32t)f2bf(a.w) << 16) | f2bf(a.z);
  o.z = ((u32t)f2bf(b.y) << 16) | f2bf(b.x);
  o.w = ((u32t)f2bf(b.w) << 16) | f2bf(b.z);
  *reinterpret_cast<uint4*>(dst + i * 8) = o;
}

__global__ void detect64(const int* __restrict__ bg, int* __restrict__ flag) {
  int t = threadIdx.x;
  int v = bg[2 * t + 1];
  unsigned long long m = __ballot(v == 0);
  if (t == 0) *flag = (m == ~0ull) ? 1 : 0;
}

__global__ __launch_bounds__(256) void compact_bg(const int* __restrict__ bg,
                                                  const int* __restrict__ flag,
                                                  int* __restrict__ bg32, int n)
{
  int i = blockIdx.x * 256 + threadIdx.x;
  if (i < n) bg32[i] = (*flag) ? bg[2 * (size_t)i] : bg[i];
}

// ---- gather pipeline macros (all indices compile-time; named uint4 regs) ----
#define GLOAD(D0, D1, D2, D3, rr) { \
  int i0_ = __shfl(idx_all, (rr) * 8 + 0 + half); \
  int i1_ = __shfl(idx_all, (rr) * 8 + 2 + half); \
  int i2_ = __shfl(idx_all, (rr) * 8 + 4 + half); \
  int i3_ = __shfl(idx_all, (rr) * 8 + 6 + half); \
  D0 = *reinterpret_cast<const uint4*>(Cin + (size_t)i0_ * 128 + l5 * 4); \
  D1 = *reinterpret_cast<const uint4*>(Cin + (size_t)i1_ * 128 + l5 * 4); \
  D2 = *reinterpret_cast<const uint4*>(Cin + (size_t)i2_ * 128 + l5 * 4); \
  D3 = *reinterpret_cast<const uint4*>(Cin + (size_t)i3_ * 128 + l5 * 4); \
}

#define PRT(D) { \
  float hv_, pv_; \
  hv_ = ubits(D.x << 16); pv_ = ubits(D.x & 0xffff0000u); s0_ += hv_; g0_ += fsig(r10_ + pv_) * hv_; \
  hv_ = ubits(D.y << 16); pv_ = ubits(D.y & 0xffff0000u); s1_ += hv_; g1_ += fsig(r11_ + pv_) * hv_; \
  hv_ = ubits(D.z << 16); pv_ = ubits(D.z & 0xffff0000u); s2_ += hv_; g2_ += fsig(r12_ + pv_) * hv_; \
  hv_ = ubits(D.w << 16); pv_ = ubits(D.w & 0xffff0000u); s3_ += hv_; g3_ += fsig(r13_ + pv_) * hv_; \
}

#define GPROC(D0, D1, D2, D3, rr) { \
  const int row_ = wave * 8 + (rr); \
  uint2 r1p_ = *reinterpret_cast<const uint2*>(s_R1 + row_ * 136 + l5 * 4); \
  float r10_ = ubits(r1p_.x << 16), r11_ = ubits(r1p_.x & 0xffff0000u); \
  float r12_ = ubits(r1p_.y << 16), r13_ = ubits(r1p_.y & 0xffff0000u); \
  float s0_ = 0.f, s1_ = 0.f, s2_ = 0.f, s3_ = 0.f; \
  float g0_ = 0.f, g1_ = 0.f, g2_ = 0.f, g3_ = 0.f; \
  PRT(D0) PRT(D1) PRT(D2) PRT(D3) \
  s0_ += __shfl_xor(s0_, 32); g0_ += __shfl_xor(g0_, 32); \
  s1_ += __shfl_xor(s1_, 32); g1_ += __shfl_xor(g1_, 32); \
  s2_ += __shfl_xor(s2_, 32); g2_ += __shfl_xor(g2_, 32); \
  s3_ += __shfl_xor(s3_, 32); g3_ += __shfl_xor(g3_, 32); \
  if (half == 0) { \
    uint2 sp_, gp_; \
    sp_.x = ((u32t)f2bf(s1_) << 16) | f2bf(s0_); \
    sp_.y = ((u32t)f2bf(s3_) << 16) | f2bf(s2_); \
    gp_.x = ((u32t)f2bf(g1_) << 16) | f2bf(g0_); \
    gp_.y = ((u32t)f2bf(g3_) << 16) | f2bf(g2_); \
    *reinterpret_cast<uint2*>(s_sb + row_ * 136 + l5 * 4) = sp_; \
    *reinterpret_cast<uint2*>(s_gb + row_ * 136 + l5 * 4) = gp_; \
  } \
}

// LDS map (26112 B -> 6 blocks/CU):
//  R0 [0,8704)      s_fm u16[32][136]; aliased by s_sb after the post-R1 barrier
//  R1 [8704,17408)  s_R1 u16[32][136]; aliased by MODE2 fp32 out-stage (with R2)
//  R2 [17408,26112) s_gb u16[32][136]
template<int MODE>   // 0=first step (h=0), 1=middle (packed out), 2=last (fp32 out)
__global__ __launch_bounds__(256, 5) void step_k(
    const float* __restrict__ fmess,
    const u16t* __restrict__ fmb,
    const int*  __restrict__ bg32,
    const u32t* __restrict__ Cin,
    const short* __restrict__ wbf,
    const float* __restrict__ bz, const float* __restrict__ urb, const float* __restrict__ bh,
    u32t* __restrict__ Cout, float* __restrict__ houtf, int E)
{
  __shared__ __align__(16) char smem[26112];
  u16t* s_fm = (u16t*)smem;
  u16t* s_sb = (u16t*)smem;             // alias of s_fm (dead after af loads + barrier)
  u16t* s_R1 = (u16t*)(smem + 8704);
  u16t* s_gb = (u16t*)(smem + 17408);

  const int tid = threadIdx.x, wave = tid >> 6, lane = tid & 63;
  const int cl = lane & 15, kg = lane >> 4;
  const int l5 = lane & 31, half = lane >> 5;
  const int base = blockIdx.x * 32;
  const int mrow = (wave & 1) * 16, ncol = (wave >> 1) * 64;

  // ---- phase 1: fmess tile -> LDS bf16 ; neighbor indices -> regs ----
  if (fmb) {
    #pragma unroll
    for (int it = 0; it < 2; ++it) {
      int s = it * 256 + tid;
      int r = s >> 4, c = (s & 15) * 8;
      uint4 v = {0u, 0u, 0u, 0u};
      int e = base + r;
      if (e < E) v = *reinterpret_cast<const uint4*>(fmb + (size_t)e * 128 + c);
      *reinterpret_cast<uint4*>(s_fm + r * 136 + c) = v;
    }
  } else {
    #pragma unroll
    for (int it = 0; it < 4; ++it) {
      int s = it * 256 + tid;
      int r = s >> 5, c = (s & 31) << 2;
      float4 v = {0.f, 0.f, 0.f, 0.f};
      int e = base + r;
      if (e < E) v = *reinterpret_cast<const float4*>(fmess + (size_t)e * 128 + c);
      s_fm[r * 136 + c]     = f2bf(v.x);
      s_fm[r * 136 + c + 1] = f2bf(v.y);
      s_fm[r * 136 + c + 2] = f2bf(v.z);
      s_fm[r * 136 + c + 3] = f2bf(v.w);
    }
  }
  int idx_all = 0;
  if (MODE != 0) {
    int er = base + wave * 8 + (lane >> 3);
    if (er >= E) er = 0;
    idx_all = bg32[(size_t)er * 8 + (lane & 7)];
  }
  __syncthreads();

  const short* Wzf = wbf;
  const short* Wzh = wbf + 16384;
  const short* Wr  = wbf + 2 * 16384;
  const short* Whf = wbf + 3 * 16384;
  const short* Whh = wbf + 4 * 16384;
  const short* Ur  = wbf + 5 * 16384;

  bf16x8 af[4];
  #pragma unroll
  for (int ks = 0; ks < 4; ++ks)
    af[ks] = *reinterpret_cast<const bf16x8*>(s_fm + (mrow + cl) * 136 + ks * 32 + kg * 8);

  // ---- phase 2: R1 = fmess @ Wr^T + urb -> s_R1 ; then gather ----
  if (MODE != 0) {
    {
      f32x4 racc[4];
      #pragma unroll
      for (int nt = 0; nt < 4; ++nt) racc[nt] = (f32x4){0.f, 0.f, 0.f, 0.f};
      #pragma unroll
      for (int ks = 0; ks < 4; ++ks) {
        #pragma unroll
        for (int nt = 0; nt < 4; ++nt) {
          bf16x8 b = *reinterpret_cast<const bf16x8*>(Wr + (size_t)(ncol + nt * 16 + cl) * 128 + ks * 32 + kg * 8);
          racc[nt] = __builtin_amdgcn_mfma_f32_16x16x32_bf16(af[ks], b, racc[nt], 0, 0, 0);
        }
      }
      #pragma unroll
      for (int nt = 0; nt < 4; ++nt) {
        int n = ncol + nt * 16 + cl;
        float bias = urb[n];
        #pragma unroll
        for (int r = 0; r < 4; ++r)
          s_R1[(mrow + kg * 4 + r) * 136 + n] = f2bf(racc[nt][r] + bias);
      }
    }
    __syncthreads();   // s_R1 visible; all af loads done -> s_fm region (s_sb) reusable

    // ---- phase 3: pipelined gather, 2-deep register double-buffer ----
    uint4 A0, A1, A2, A3, B0, B1, B2, B3;
    GLOAD(A0, A1, A2, A3, 0)
    GLOAD(B0, B1, B2, B3, 1) GPROC(A0, A1, A2, A3, 0)
    GLOAD(A0, A1, A2, A3, 2) GPROC(B0, B1, B2, B3, 1)
    GLOAD(B0, B1, B2, B3, 3) GPROC(A0, A1, A2, A3, 2)
    GLOAD(A0, A1, A2, A3, 4) GPROC(B0, B1, B2, B3, 3)
    GLOAD(B0, B1, B2, B3, 5) GPROC(A0, A1, A2, A3, 4)
    GLOAD(A0, A1, A2, A3, 6) GPROC(B0, B1, B2, B3, 5)
    GLOAD(B0, B1, B2, B3, 7) GPROC(A0, A1, A2, A3, 6)
    GPROC(B0, B1, B2, B3, 7)
    __syncthreads();   // s_sb/s_gb complete
  }

  // ---- phase 4a: z = sigmoid(Wzf·fm + Wzh·sum + bz) ----
  float zv[4][4];
  {
    f32x4 t0[4], t1[4];
    #pragma unroll
    for (int nt = 0; nt < 4; ++nt) { t0[nt] = (f32x4){0.f, 0.f, 0.f, 0.f}; t1[nt] = (f32x4){0.f, 0.f, 0.f, 0.f}; }
    #pragma unroll
    for (int ks = 0; ks < 4; ++ks) {
      #pragma unroll
      for (int nt = 0; nt < 4; ++nt) {
        int n = ncol + nt * 16 + cl;
        bf16x8 b1 = *reinterpret_cast<const bf16x8*>(Wzf + (size_t)n * 128 + ks * 32 + kg * 8);
        t0[nt] = __builtin_amdgcn_mfma_f32_16x16x32_bf16(af[ks], b1, t0[nt], 0, 0, 0);
        if (MODE != 0) {
          bf16x8 az = *reinterpret_cast<const bf16x8*>(s_sb + (mrow + cl) * 136 + ks * 32 + kg * 8);
          bf16x8 b2 = *reinterpret_cast<const bf16x8*>(Wzh + (size_t)n * 128 + ks * 32 + kg * 8);
          t1[nt] = __builtin_amdgcn_mfma_f32_16x16x32_bf16(az, b2, t1[nt], 0, 0, 0);
        }
      }
    }
    #pragma unroll
    for (int nt = 0; nt < 4; ++nt) {
      int n = ncol + nt * 16 + cl;
      float bzv = bz[n];
      #pragma unroll
      for (int r = 0; r < 4; ++r)
        zv[nt][r] = fsig(t0[nt][r] + t1[nt][r] + bzv);
    }
  }

  // ---- phase 4b: pre = tanh(Whf·fm + Whh·gated + bh) ; epilogue ----
  float nh_sv[4][4];
  {
    f32x4 t0[4], t1[4];
    #pragma unroll
    for (int nt = 0; nt < 4; ++nt) { t0[nt] = (f32x4){0.f, 0.f, 0.f, 0.f}; t1[nt] = (f32x4){0.f, 0.f, 0.f, 0.f}; }
    #pragma unroll
    for (int ks = 0; ks < 4; ++ks) {
      #pragma unroll
      for (int nt = 0; nt < 4; ++nt) {
        int n = ncol + nt * 16 + cl;
        bf16x8 b1 = *reinterpret_cast<const bf16x8*>(Whf + (size_t)n * 128 + ks * 32 + kg * 8);
        t0[nt] = __builtin_amdgcn_mfma_f32_16x16x32_bf16(af[ks], b1, t0[nt], 0, 0, 0);
        if (MODE != 0) {
          bf16x8 ag = *reinterpret_cast<const bf16x8*>(s_gb + (mrow + cl) * 136 + ks * 32 + kg * 8);
          bf16x8 b2 = *reinterpret_cast<const bf16x8*>(Whh + (size_t)n * 128 + ks * 32 + kg * 8);
          t1[nt] = __builtin_amdgcn_mfma_f32_16x16x32_bf16(ag, b2, t1[nt], 0, 0, 0);
        }
      }
    }
    #pragma unroll
    for (int nt = 0; nt < 4; ++nt) {
      int n = ncol + nt * 16 + cl;
      float bhv = bh[n];
      #pragma unroll
      for (int r = 0; r < 4; ++r) {
        int rowt = mrow + kg * 4 + r;
        int e = base + rowt;
        float pre = ftanh(t0[nt][r] + t1[nt][r] + bhv);
        float sh  = (MODE == 0) ? 0.f : bf2f(s_sb[rowt * 136 + n]);
        float z   = zv[nt][r];
        float nh  = (1.f - z) * sh + z * pre;
        if (e == 0) nh = 0.f;
        nh_sv[nt][r] = nh;
      }
    }
  }

  // ---- phase 6 ----
  if (MODE == 2) {
    __syncthreads();   // all s_gb/s_sb readers done
    float* so = (float*)(smem + 8704);   // 16 KB stage over R1+R2
    #pragma unroll
    for (int nt = 0; nt < 4; ++nt) {
      int n = ncol + nt * 16 + cl;
      #pragma unroll
      for (int r = 0; r < 4; ++r)
        so[(mrow + kg * 4 + r) * 128 + n] = nh_sv[nt][r];
    }
    __syncthreads();
    #pragma unroll
    for (int it = 0; it < 4; ++it) {
      int slot = it * 256 + tid;
      int row = slot >> 5, seg = slot & 31;
      if (base + row < E)
        *reinterpret_cast<float4*>(houtf + (size_t)(base + row) * 128 + seg * 4) =
            *reinterpret_cast<const float4*>(so + row * 128 + seg * 4);
    }
  } else {
    // P_next = h_next @ Ur^T ; store packed (P<<16)|h
    __syncthreads();   // all s_sb readers (frags, sh) done before overwrite
    #pragma unroll
    for (int nt = 0; nt < 4; ++nt) {
      int n = ncol + nt * 16 + cl;
      #pragma unroll
      for (int r = 0; r < 4; ++r)
        s_sb[(mrow + kg * 4 + r) * 136 + n] = f2bf(nh_sv[nt][r]);
    }
    __syncthreads();
    f32x4 pacc[4];
    #pragma unroll
    for (int nt = 0; nt < 4; ++nt) pacc[nt] = (f32x4){0.f, 0.f, 0.f, 0.f};
    #pragma unroll
    for (int ks = 0; ks < 4; ++ks) {
      bf16x8 ah = *reinterpret_cast<const bf16x8*>(s_sb + (mrow + cl) * 136 + ks * 32 + kg * 8);
      #pragma unroll
      for (int nt = 0; nt < 4; ++nt) {
        bf16x8 b = *reinterpret_cast<const bf16x8*>(Ur + (size_t)(ncol + nt * 16 + cl) * 128 + ks * 32 + kg * 8);
        pacc[nt] = __builtin_amdgcn_mfma_f32_16x16x32_bf16(ah, b, pacc[nt], 0, 0, 0);
      }
    }
    #pragma unroll
    for (int nt = 0; nt < 4; ++nt) {
      int n = ncol + nt * 16 + cl;
      #pragma unroll
      for (int r = 0; r < 4; ++r) {
        int e = base + mrow + kg * 4 + r;
        if (e < E) {
          u32t pk = ((u32t)f2bf(pacc[nt][r]) << 16) | f2bf(nh_sv[nt][r]);
          Cout[(size_t)e * 128 + n] = pk;
        }
      }
    }
  }
}

extern "C" void kernel_launch(void* const* d_in, const int* in_sizes, int n_in,
                              void* d_out, int out_size, void* d_ws, size_t ws_size,
                              hipStream_t stream) {
  const float* fmess = (const float*)d_in[0];
  const int*   bg    = (const int*)d_in[1];
  const float* Wz    = (const float*)d_in[2];
  const float* bz    = (const float*)d_in[3];
  const float* Wrw   = (const float*)d_in[4];
  const float* Urw   = (const float*)d_in[5];
  const float* urb   = (const float*)d_in[6];
  const float* Wh    = (const float*)d_in[7];
  const float* bh    = (const float*)d_in[8];
  float* out = (float*)d_out;

  const int E = in_sizes[0] / 128;
  const size_t EH = (size_t)E * 128;
  const size_t wshorts = 6 * 16384;

  u32t* CB = (u32t*)d_out;   // d_out doubles as packed scratch until the last step
  u32t* CA = (u32t*)d_ws;

  // ws layout: CA (EH u32) | [fmb (EH u16)] | bg32 (E*8 int) | wbf | flag
  u16t* fmb = nullptr;
  char* p = (char*)(CA + EH);
  size_t need_full = EH * 4 + EH * 2 + (size_t)E * 8 * 4 + wshorts * 2 + 64;
  if (ws_size >= need_full) {
    fmb = (u16t*)p;
    p = (char*)(fmb + EH);
  }
  int* bg32 = (int*)p;
  short* wbf = (short*)(bg32 + (size_t)E * 8);
  int* flag = (int*)(wbf + wshorts);

  conv_weights<<<384, 256, 0, stream>>>(Wz, Wrw, Urw, Wh, wbf);
  detect64<<<1, 64, 0, stream>>>(bg, flag);
  compact_bg<<<(E * 8 + 255) / 256, 256, 0, stream>>>(bg, flag, bg32, E * 8);
  if (fmb) conv_fmess<<<(int)((EH / 8 + 255) / 256), 256, 0, stream>>>(fmess, fmb, EH / 8);

  const int grid = (E + 31) / 32;
  // s0 -> CB ; s1 CB->CA ; s2 CA->CB ; s3 CB->CA ; s4 CA -> fp32 out
  step_k<0><<<grid, 256, 0, stream>>>(fmess, fmb, bg32, nullptr, wbf, bz, urb, bh, CB, nullptr, E);
  step_k<1><<<grid, 256, 0, stream>>>(fmess, fmb, bg32, CB, wbf, bz, urb, bh, CA, nullptr, E);
  step_k<1><<<grid, 256, 0, stream>>>(fmess, fmb, bg32, CA, wbf, bz, urb, bh, CB, nullptr, E);
  step_k<1><<<grid, 256, 0, stream>>>(fmess, fmb, bg32, CB, wbf, bz, urb, bh, CA, nullptr, E);
  step_k<2><<<grid, 256, 0, stream>>>(fmess, fmb, bg32, CA, wbf, bz, urb, bh, nullptr, out, E);
}